// Round 8
// baseline (25.463 us; speedup 1.0000x reference)
//
#include <hip/hip_runtime.h>
#include <cfloat>

// Problem constants (from reference): B=8, C=2, H=256, W=256
#define BB 8
#define CC 2
#define HH 256
#define WW 256

typedef unsigned long long ull;

static constexpr float EDT_INF = 1e4f;          // matches reference INF
static constexpr int   NPIX    = BB * HH * WW;  // 524288

// ---------------------------------------------------------------------------
// Distance^2 to nearest SET bit of zm (the zeros of the selected field),
// reproducing the reference f32 scan exactly (sentinels 1e4+pos+1 / 1e4+256-pos,
// g = fminf(fwd,bwd), return g*g).
__device__ __forceinline__ float hdist2(const ull* zm, int pos) {
    float fwd = EDT_INF + (float)(pos + 1);
    {
        int k = pos - 1;
        if (k >= 0) {
            int w = k >> 6;
            ull t = zm[w] & (~0ULL >> (63 - (k & 63)));
            for (;;) {
                if (t) { int j = (w << 6) + 63 - __builtin_clzll(t); fwd = (float)(pos - j); break; }
                if (--w < 0) break;
                t = zm[w];
            }
        }
    }
    float bwd = EDT_INF + (float)(256 - pos);
    {
        int k = pos + 1;
        if (k < 256) {
            int w = k >> 6;
            ull t = zm[w] & (~0ULL << (k & 63));
            for (;;) {
                if (t) { int j = (w << 6) + __builtin_ctzll(t); bwd = (float)(j - pos); break; }
                if (++w >= 4) break;
                t = zm[w];
            }
        }
    }
    float g = fminf(fwd, bwd);
    return g * g;
}

// Nearest SET bit distance (int), large sentinel when none.
__device__ __forceinline__ int nearest_set(const ull* zm, int pos) {
    int best = 1 << 20;
    {
        int k = pos - 1;
        if (k >= 0) {
            int w = k >> 6;
            ull t = zm[w] & (~0ULL >> (63 - (k & 63)));
            for (;;) {
                if (t) { int j = (w << 6) + 63 - __builtin_clzll(t); best = pos - j; break; }
                if (--w < 0) break;
                t = zm[w];
            }
        }
    }
    {
        int k = pos + 1;
        if (k < 256) {
            int w = k >> 6;
            ull t = zm[w] & (~0ULL << (k & 63));
            for (;;) {
                if (t) { int j = (w << 6) + __builtin_ctzll(t); best = min(best, j - pos); break; }
                if (++w >= 4) break;
                t = zm[w];
            }
        }
    }
    return best;
}

// ---------------------------------------------------------------------------
// K1: build ROW masks (coalesced: lanes across w) + per-block tmin partials.
__global__ void k_masks(const float* __restrict__ preds,
                        const int*   __restrict__ target,
                        ull* __restrict__ mPC, ull* __restrict__ mGT0,
                        ull* __restrict__ mG255, int* __restrict__ tminPart) {
    const int blk = blockIdx.x;
    const int b  = blk >> 5;               // image
    const int ig = blk & 31;               // 8-row group
    const int wv = threadIdx.x >> 6;       // word index 0..3
    const int ln = threadIdx.x & 63;
    const int w  = (wv << 6) | ln;

    int tmin = 0x7fffffff;
#pragma unroll
    for (int r = 0; r < 8; ++r) {
        int i = ig * 8 + r;
        float a0 = preds[((size_t)b * CC + 0) * HH * WW + (size_t)i * WW + w];
        float a1 = preds[((size_t)b * CC + 1) * HH * WW + (size_t)i * WW + w];
        bool pc = (a1 > a0);               // argmax over C=2, ties -> class 0
        int tv = target[((size_t)b * HH + i) * WW + w];
        tmin = min(tmin, tv);
        ull bp = __ballot(pc);
        ull b0 = __ballot(tv > 0);
        ull b2 = __ballot(tv == 255);
        if (ln == 0) {
            size_t midx = ((size_t)b * HH + i) * 4 + wv;
            mPC[midx] = bp; mGT0[midx] = b0; mG255[midx] = b2;
        }
    }
    for (int off = 32; off > 0; off >>= 1) tmin = min(tmin, __shfl_down(tmin, off));
    __shared__ int swv[4];
    if (ln == 0) swv[wv] = tmin;
    __syncthreads();
    if (threadIdx.x == 0)
        tminPart[blk] = min(min(swv[0], swv[1]), min(swv[2], swv[3]));
}

// ---------------------------------------------------------------------------
// K2: fused per-COLUMN kernel. Axis-swapped separable EDT with polarity
// pruning: for pixel (i,j) polarity P, opposite-polarity rows have field
// value 0 -> candidate d^2; nearest opposite row dv (from column ballot
// mask, clz/ctz) caps the search: EDT^2 = min(own_h2,
// min_{d<dv}(d^2 + s[i+-d]), dv^2). Exact (f32 add of nonneg is monotone,
// all small values integer-exact). Only 2 hdist2 calls per thread.
__global__ void k_fused(const int* __restrict__ target,
                        const ull* __restrict__ mPC,
                        const ull* __restrict__ mGT0,
                        const ull* __restrict__ mG255,
                        const int* __restrict__ tminPart,
                        float* __restrict__ partials) {
    const int blk = blockIdx.x;            // b*256 + j
    const int b = blk >> 8, j = blk & 255;
    const int i = threadIdx.x;             // row
    const int wv = i >> 6, ln = i & 63;

    // tmin = min of the 256 k_masks partials: wave shfl + 4-entry merge
    __shared__ int stw[4];
    {
        int v = tminPart[i];
        for (int off = 32; off > 0; off >>= 1) v = min(v, __shfl_down(v, off));
        if (ln == 0) stw[wv] = v;
    }
    __syncthreads();
    const int tmin = min(min(stw[0], stw[1]), min(stw[2], stw[3]));
    const bool allpos = (tmin > 0);

    // row i's masks: 4 consecutive ULLs each -> coalesced loads
    ull wp[4], wg[4];
    {
        const ull* pP = mPC   + ((size_t)b * HH + i) * 4;
        const ull* p0 = mGT0  + ((size_t)b * HH + i) * 4;
        const ull* p2 = mG255 + ((size_t)b * HH + i) * 4;
#pragma unroll
        for (int k = 0; k < 4; ++k) {
            wp[k] = pP[k];
            ull g = p0[k];
            if (!allpos) g &= ~p2[k];      // 255 -> tmin==0 -> not >0
            wg[k] = g;
        }
    }
    const bool pc = (wp[j >> 6] >> (j & 63)) & 1ULL;
    const bool gt = (wg[j >> 6] >> (j & 63)) & 1ULL;

    // own-polarity zero-masks (zeros of my field = bits differing from mine)
    ull zp[4], zg[4];
#pragma unroll
    for (int k = 0; k < 4; ++k) {
        zp[k] = pc ? ~wp[k] : wp[k];
        zg[k] = gt ? ~wg[k] : wg[k];
    }

    // horizontal distance^2 for own polarity fields + column polarity masks
    __shared__ float s_p[HH], s_g[HH];
    __shared__ ull cshP[4], cshG[4];
    s_p[i] = hdist2(zp, j);
    s_g[i] = hdist2(zg, j);
    {
        ull bp = __ballot(pc);
        ull bg = __ballot(gt);
        if (ln == 0) { cshP[wv] = bp; cshG[wv] = bg; }
    }
    __syncthreads();

    // column opposite-polarity masks in registers
    ull cp[4], cg[4];
#pragma unroll
    for (int k = 0; k < 4; ++k) {
        ull P = cshP[k], G = cshG[k];
        cp[k] = pc ? ~P : P;
        cg[k] = gt ? ~G : G;
    }
    const int dvp = nearest_set(cp, i);
    const int dvg = nearest_set(cg, i);

    // --- pc vertical search, pruned ---
    float mn = s_p[i];
    {
        int dmax = min(dvp, HH);
        for (int d = 1; d < dmax; ++d) {
            float dd = (float)(d * d);
            if (dd >= mn) break;
            int kl = i - d, kr = i + d;
            if (kl >= 0) mn = fminf(mn, dd + s_p[kl]);
            if (kr < HH) mn = fminf(mn, dd + s_p[kr]);
        }
        float dv = (float)dvp;
        mn = fminf(mn, dv * dv);
    }
    float pd = sqrtf(mn);

    // --- gt vertical search, pruned ---
    float mg = s_g[i];
    {
        int dmax = min(dvg, HH);
        for (int d = 1; d < dmax; ++d) {
            float dd = (float)(d * d);
            if (dd >= mg) break;
            int kl = i - d, kr = i + d;
            if (kl >= 0) mg = fminf(mg, dd + s_g[kl]);
            if (kr < HH) mg = fminf(mg, dd + s_g[kr]);
        }
        float dv = (float)dvg;
        mg = fminf(mg, dv * dv);
    }
    float gd = sqrtf(mg);

    // --- final elementwise math (reference op order) ---
    int tv = target[((size_t)b * HH + i) * WW + j];   // uncoalesced, L2-fed
    if (tv == 255) tv = tmin;
    float gtv = (float)tv;
    float pcv = pc ? 1.0f : 0.0f;
    float err  = fabsf(gtv - pcv);
    float dist = sqrtf(pd * pd + gd * gd);
    float mult = sqrtf(err * dist + 1e-9f);

    // deterministic block sum: wave shfl-add + fixed-order 4-term merge
    __shared__ float sws[4];
    for (int off = 32; off > 0; off >>= 1) mult += __shfl_down(mult, off);
    if (ln == 0) sws[wv] = mult;
    __syncthreads();
    if (i == 0) partials[blk] = ((sws[0] + sws[1]) + sws[2]) + sws[3];
}

// ---------------------------------------------------------------------------
// K3: final deterministic reduction of B*W partials -> mean (fixed order)
__global__ void k_final(const float* __restrict__ partials, float* __restrict__ out) {
    __shared__ float s[256];
    float acc = 0.0f;
    for (int k = threadIdx.x; k < BB * WW; k += 256) acc += partials[k];
    s[threadIdx.x] = acc;
    __syncthreads();
    for (int st = 128; st > 0; st >>= 1) {
        if (threadIdx.x < st) s[threadIdx.x] += s[threadIdx.x + st];
        __syncthreads();
    }
    if (threadIdx.x == 0) out[0] = s[0] * (1.0f / (float)NPIX);  // /2^19: exact
}

// ---------------------------------------------------------------------------
extern "C" void kernel_launch(void* const* d_in, const int* in_sizes, int n_in,
                              void* d_out, int out_size, void* d_ws, size_t ws_size,
                              hipStream_t stream) {
    const float* preds  = (const float*)d_in[0];
    const int*   target = (const int*)d_in[1];
    float* out = (float*)d_out;

    // ws layout: 3 mask arrays (64 KB each), partials, tmin partials
    ull* mPC   = (ull*)d_ws;                         // 8*256*4 ULL
    ull* mGT0  = mPC  + (size_t)BB * HH * 4;
    ull* mG255 = mGT0 + (size_t)BB * HH * 4;
    float* partials = (float*)(mG255 + (size_t)BB * HH * 4);   // B*W floats
    int*   tminPart = (int*)(partials + BB * WW);              // 256 ints

    k_masks<<<256, 256, 0, stream>>>(preds, target, mPC, mGT0, mG255, tminPart);
    k_fused<<<BB * WW, HH, 0, stream>>>(target, mPC, mGT0, mG255, tminPart, partials);
    k_final<<<1, 256, 0, stream>>>(partials, out);
}